// Round 4
// baseline (308.207 us; speedup 1.0000x reference)
//
#include <hip/hip_runtime.h>
#include <hip/hip_bf16.h>
#include <math.h>

// EntityAwareAttention on MI355X.
// K1: W_hid -> bf16, transposed/padded [22 kchunks][64 a][32 k]
// K2: u2[b][a] entity projection (fp32), 2 batches per block, grid 1024
// K3: main fused kernel, one block per (b, 16-token octant):
//       stage X=concat(hidden,pos1,pos2) as bf16 in LDS (single HBM read),
//       W STREAMED from L2 in the K-loop (unroll 4, ~4 loads in flight,
//       no persistent W registers -> low VGPR, 6 blocks/CU),
//       u1 via mfma_f32_16x16x32_bf16 (barrier-free K-loop),
//       scores=v.tanh(u1+u2), partial softmax (m,S) + z-partial to ws.
// K4: combine 8 partials per b (log-sum-exp merge), write z.

#define B_    2048
#define L_    128
#define H2_   600
#define P_    50
#define A_    50
#define D700  700
#define KCN   22      // ceil(700/32) -> 704
#define AP    64      // padded attention dim
#define MT    16      // tokens per block
#define XP    712     // Xs row stride in bf16 elems (704 data + 8 pad; 1424B = 89*16B)

typedef __attribute__((ext_vector_type(8))) short short8;
typedef __attribute__((ext_vector_type(4))) float f32x4;

__device__ __forceinline__ unsigned short f2bf(float f) {
  unsigned u = __float_as_uint(f);
  u += 0x7fffu + ((u >> 16) & 1u);   // round-to-nearest-even
  return (unsigned short)(u >> 16);
}
__device__ __forceinline__ unsigned pk2(float lo, float hi) {
  return (unsigned)f2bf(lo) | ((unsigned)f2bf(hi) << 16);
}
__device__ __forceinline__ float bf2f(unsigned short s) {
  return __uint_as_float(((unsigned)s) << 16);
}

// ---------------- K1: prep W_hid -> bf16 chunked [kc][a][k] ----------------
__global__ __launch_bounds__(256) void kwprep(const float* __restrict__ Wh,
                                              unsigned short* __restrict__ Wt) {
  int idx = blockIdx.x * 256 + threadIdx.x;
  if (idx >= KCN * 2048) return;
  int kc = idx >> 11, r = idx & 2047, a = r >> 5, kk = r & 31;
  int d = kc * 32 + kk;
  float v = (a < A_ && d < D700) ? Wh[a * D700 + d] : 0.f;
  Wt[idx] = f2bf(v);
}

// ---------------- K2: u2[b][0..63] (fp32), 2 b's per block ----------------
__global__ __launch_bounds__(256) void ku2(const float* __restrict__ hidden,
                                           const int* __restrict__ e1,
                                           const int* __restrict__ e2,
                                           const float* __restrict__ Went,
                                           const float* __restrict__ lt,
                                           float* __restrict__ u2ws) {
  __shared__ __align__(16) float E[2][2400];   // [hid_e1|e1_type|hid_e2|e2_type]
  __shared__ float dots[2][2][3];
  __shared__ float aw[2][2][3];
  int tid = threadIdx.x;
  int b0 = blockIdx.x * 2;

  for (int idx = tid; idx < 2 * 2 * 150; idx += 256) {
    int i = idx / 300, r = idx - i * 300, e = r / 150, g = r - e * 150;
    int bb = b0 + i;
    int l = e ? e2[bb] : e1[bb];
    float4 f = *(const float4*)(hidden + ((size_t)bb * L_ + l) * H2_ + g * 4);
    *(float4*)(&E[i][e * 1200 + g * 4]) = f;
  }
  __syncthreads();

  int w = tid >> 6, lane = tid & 63;
  for (int task = w * 3; task < w * 3 + 3; ++task) {
    int i = task / 6, e = (task / 3) & 1, t = task % 3;
    float p = 0.f;
    for (int d = lane; d < 600; d += 64) p += E[i][e * 1200 + d] * lt[t * 600 + d];
    #pragma unroll
    for (int mask = 1; mask <= 32; mask <<= 1) p += __shfl_xor(p, mask);
    if (lane == 0) dots[i][e][t] = p;
  }
  __syncthreads();
  if (tid < 12) {
    int t = tid % 3, e = (tid / 3) & 1, i = tid / 6;
    float d0 = dots[i][e][0], d1 = dots[i][e][1], d2 = dots[i][e][2];
    float m = fmaxf(d0, fmaxf(d1, d2));
    float x0 = expf(d0 - m), x1 = expf(d1 - m), x2 = expf(d2 - m);
    float Z = x0 + x1 + x2;
    aw[i][e][t] = ((t == 0) ? x0 : (t == 1) ? x1 : x2) / Z;
  }
  __syncthreads();
  for (int idx = tid; idx < 2 * 2 * 600; idx += 256) {
    int i = idx / 1200, r = idx - i * 1200, e = r / 600, d = r - e * 600;
    float v = aw[i][e][0] * lt[d] + aw[i][e][1] * lt[600 + d] + aw[i][e][2] * lt[1200 + d];
    E[i][e * 1200 + 600 + d] = v;
  }
  __syncthreads();
  for (int a = w; a < A_; a += 4) {
    float acc[2] = {0.f, 0.f};
    for (int d0 = lane * 4; d0 < 2400; d0 += 256) {
      float4 wv = *(const float4*)(Went + a * 2400 + d0);
      #pragma unroll
      for (int i = 0; i < 2; ++i) {
        float4 ev = *(const float4*)(&E[i][d0]);
        acc[i] += ev.x * wv.x + ev.y * wv.y + ev.z * wv.z + ev.w * wv.w;
      }
    }
    #pragma unroll
    for (int i = 0; i < 2; ++i) {
      float p = acc[i];
      #pragma unroll
      for (int mask = 1; mask <= 32; mask <<= 1) p += __shfl_xor(p, mask);
      if (lane == 0) u2ws[(b0 + i) * AP + a] = p;
    }
  }
  for (int idx = tid; idx < 2 * (AP - A_); idx += 256) {
    u2ws[(b0 + idx / (AP - A_)) * AP + A_ + idx % (AP - A_)] = 0.f;
  }
}

// ---------------- K3: main fused kernel ----------------
__global__ __launch_bounds__(256, 6) void kmain(
    const float* __restrict__ hidden, const float* __restrict__ pos1,
    const float* __restrict__ pos2, const float* __restrict__ vvec,
    const unsigned short* __restrict__ Wt, const float* __restrict__ u2ws,
    float* __restrict__ zp_ws, float* __restrict__ mS_ws) {
  __shared__ __align__(16) unsigned short Xs[MT * XP];   // 22,784 B
  __shared__ float scores4[4][MT];
  __shared__ float es_s[MT];
  __shared__ float u2s[AP];
  __shared__ float vs[AP];

  int tid = threadIdx.x;
  int bq = blockIdx.x;
  int b = bq >> 3, o = bq & 7, tok0 = o * MT;
  int lane = tid & 63, wv = tid >> 6;
  int acol = lane & 15, kgrp = lane >> 4;

  // ---- stage X (bf16): hidden cols 0..599, pos1 600..649, pos2 650..699, 0-pad 700..703
  const float* hb = hidden + ((size_t)(b * L_ + tok0)) * H2_;
  for (int idx = tid; idx < MT * 150; idx += 256) {
    int t = idx / 150, g = idx - t * 150;
    float4 f = *(const float4*)(hb + t * H2_ + g * 4);
    uint2 wvv; wvv.x = pk2(f.x, f.y); wvv.y = pk2(f.z, f.w);
    *(uint2*)(&Xs[t * XP + g * 4]) = wvv;
  }
  const float* p1 = pos1 + (size_t)(b * L_ + tok0) * P_;
  const float* p2 = pos2 + (size_t)(b * L_ + tok0) * P_;
  for (int idx = tid; idx < MT * 25; idx += 256) {
    int t = idx / 25, g = idx - t * 25;
    float2 f = *(const float2*)(p1 + t * P_ + g * 2);
    *(unsigned*)(&Xs[t * XP + 600 + g * 2]) = pk2(f.x, f.y);
  }
  for (int idx = tid; idx < MT * 25; idx += 256) {
    int t = idx / 25, g = idx - t * 25;
    float2 f = *(const float2*)(p2 + t * P_ + g * 2);
    *(unsigned*)(&Xs[t * XP + 650 + g * 2]) = pk2(f.x, f.y);
  }
  if (tid < MT * 2) {
    int t = tid >> 1, g = tid & 1;
    *(unsigned*)(&Xs[t * XP + 700 + g * 2]) = 0u;
  }
  if (tid < AP) {
    u2s[tid] = u2ws[b * AP + tid];
    vs[tid] = (tid < A_) ? vvec[tid] : 0.f;
  }
  __syncthreads();

  // ---- MFMA K-loop: D[16 tok][64 a]; W streamed from L2, barrier-free
  const unsigned short* wp = Wt + (wv * 16 + acol) * 32 + kgrp * 8;
  f32x4 acc0 = {0.f, 0.f, 0.f, 0.f};
  #pragma unroll 4
  for (int kc = 0; kc < KCN; ++kc) {
    short8 wfrag = *(const short8*)(wp + kc * 2048);
    short8 a0 = *(const short8*)(&Xs[acol * XP + kc * 32 + kgrp * 8]);
    acc0 = __builtin_amdgcn_mfma_f32_16x16x32_bf16(a0, wfrag, acc0, 0, 0, 0);
  }

  // ---- epilogue: scores = sum_a v[a]*tanh(u1+u2)
  {
    float va = vs[wv * 16 + acol];
    float u2a = u2s[wv * 16 + acol];
    float s0[4];
    #pragma unroll
    for (int r = 0; r < 4; ++r) s0[r] = va * tanhf(acc0[r] + u2a);
    #pragma unroll
    for (int mask = 1; mask < 16; mask <<= 1) {
      #pragma unroll
      for (int r = 0; r < 4; ++r) s0[r] += __shfl_xor(s0[r], mask);
    }
    if (acol == 0) {
      #pragma unroll
      for (int r = 0; r < 4; ++r) scores4[wv][kgrp * 4 + r] = s0[r];
    }
  }
  __syncthreads();

  // ---- partial softmax over this block's 16 tokens
  if (tid < 64) {
    float s = (tid < MT)
                  ? (scores4[0][tid] + scores4[1][tid] + scores4[2][tid] + scores4[3][tid])
                  : -3.402823466e38f;
    float m = s;
    #pragma unroll
    for (int mask = 1; mask <= 32; mask <<= 1) m = fmaxf(m, __shfl_xor(m, mask));
    float e = (tid < MT) ? expf(s - m) : 0.f;
    float S = e;
    #pragma unroll
    for (int mask = 1; mask <= 32; mask <<= 1) S += __shfl_xor(S, mask);
    if (tid < MT) es_s[tid] = e;
    if (tid == 0) { mS_ws[bq * 2] = m; mS_ws[bq * 2 + 1] = S; }
  }
  __syncthreads();

  // ---- z-partial: zp[d] = sum_l exp(s_l - m) * hidden_bf16[l][d]
  if (tid < 75) {
    float acc[8] = {0.f, 0.f, 0.f, 0.f, 0.f, 0.f, 0.f, 0.f};
    #pragma unroll
    for (int t = 0; t < MT; ++t) {
      short8 xv = *(const short8*)(&Xs[t * XP + tid * 8]);
      float e = es_s[t];
      #pragma unroll
      for (int j = 0; j < 8; ++j) acc[j] += e * bf2f((unsigned short)xv[j]);
    }
    float4 w0 = {acc[0], acc[1], acc[2], acc[3]};
    float4 w1 = {acc[4], acc[5], acc[6], acc[7]};
    *(float4*)(zp_ws + (size_t)bq * 600 + tid * 8) = w0;
    *(float4*)(zp_ws + (size_t)bq * 600 + tid * 8 + 4) = w1;
  }
}

// ---------------- K4: combine 8 partials per b ----------------
__global__ __launch_bounds__(128) void kcomb(const float* __restrict__ zp_ws,
                                             const float* __restrict__ mS_ws,
                                             float* __restrict__ out) {
  int b = blockIdx.x, tid = threadIdx.x;
  float mq[8], Sq[8];
  #pragma unroll
  for (int qq = 0; qq < 8; ++qq) {
    mq[qq] = mS_ws[(b * 8 + qq) * 2];
    Sq[qq] = mS_ws[(b * 8 + qq) * 2 + 1];
  }
  float M = mq[0];
  #pragma unroll
  for (int qq = 1; qq < 8; ++qq) M = fmaxf(M, mq[qq]);
  float c[8], Z = 0.f;
  #pragma unroll
  for (int qq = 0; qq < 8; ++qq) { c[qq] = expf(mq[qq] - M); Z += Sq[qq] * c[qq]; }
  float inv = 1.f / Z;
  for (int d = tid; d < 600; d += 128) {
    float z = 0.f;
    #pragma unroll
    for (int qq = 0; qq < 8; ++qq) z += c[qq] * zp_ws[(size_t)(b * 8 + qq) * 600 + d];
    out[b * 600 + d] = z * inv;
  }
}

extern "C" void kernel_launch(void* const* d_in, const int* in_sizes, int n_in,
                              void* d_out, int out_size, void* d_ws, size_t ws_size,
                              hipStream_t stream) {
  const float* hidden = (const float*)d_in[0];
  const float* pos1   = (const float*)d_in[1];
  const float* pos2   = (const float*)d_in[2];
  const int*   e1     = (const int*)d_in[3];
  const int*   e2     = (const int*)d_in[4];
  const float* Whid   = (const float*)d_in[5];
  const float* Went   = (const float*)d_in[6];
  const float* lt     = (const float*)d_in[7];
  const float* vvec   = (const float*)d_in[8];
  float* out = (float*)d_out;

  char* ws = (char*)d_ws;
  unsigned short* Wt = (unsigned short*)ws;                       //  90,112 B (pad 98,304)
  float* u2ws  = (float*)(ws + 98304);                            // 524,288 B
  float* mS_ws = (float*)(ws + 98304 + 524288);                   // 131,072 B
  float* zp_ws = (float*)(ws + 98304 + 524288 + 131072);          // 39,321,600 B

  hipLaunchKernelGGL(kwprep, dim3(176), dim3(256), 0, stream, Whid, Wt);
  hipLaunchKernelGGL(ku2, dim3(B_ / 2), dim3(256), 0, stream, hidden, e1, e2, Went, lt, u2ws);
  hipLaunchKernelGGL(kmain, dim3(B_ * 8), dim3(256), 0, stream, hidden, pos1, pos2, vvec,
                     Wt, u2ws, zp_ws, mS_ws);
  hipLaunchKernelGGL(kcomb, dim3(B_), dim3(128), 0, stream, zp_ws, mS_ws, out);
}

// Round 5
// 272.533 us; speedup vs baseline: 1.1309x; 1.1309x over previous
//
#include <hip/hip_runtime.h>
#include <hip/hip_bf16.h>
#include <math.h>

// EntityAwareAttention on MI355X.
// K1: W_hid -> bf16, transposed/padded [22 kchunks][64 a][32 k]
// K2: u2[b][a] entity projection (fp32), 2 batches per block, grid 1024
// K3: main fused kernel, one block per (b, 16-token octant):
//       BATCHED register staging: all ~14 global loads issued before any
//       convert/ds_write (deep VMEM queue -> HBM saturation),
//       X=concat(hidden,pos1,pos2) as bf16 in LDS,
//       W fragments in registers (two 11-chunk halves, half2 prefetched
//       under the first 11 MFMAs), barrier-free MFMA K-loop,
//       scores=v.tanh(u1+u2), partial softmax (m,S) + z-partial to ws.
// K4: combine 8 partials per b (log-sum-exp merge), write z.

#define B_    2048
#define L_    128
#define H2_   600
#define P_    50
#define A_    50
#define D700  700
#define KCN   22      // ceil(700/32) -> 704
#define KH    11      // half of KCN
#define AP    64      // padded attention dim
#define MT    16      // tokens per block
#define XP    712     // Xs row stride in bf16 elems (704 data + 8 pad; 1424B = 89*16B)

typedef __attribute__((ext_vector_type(8))) short short8;
typedef __attribute__((ext_vector_type(4))) float f32x4;

__device__ __forceinline__ unsigned short f2bf(float f) {
  unsigned u = __float_as_uint(f);
  u += 0x7fffu + ((u >> 16) & 1u);   // round-to-nearest-even
  return (unsigned short)(u >> 16);
}
__device__ __forceinline__ unsigned pk2(float lo, float hi) {
  return (unsigned)f2bf(lo) | ((unsigned)f2bf(hi) << 16);
}
__device__ __forceinline__ float bf2f(unsigned short s) {
  return __uint_as_float(((unsigned)s) << 16);
}

// ---------------- K1: prep W_hid -> bf16 chunked [kc][a][k] ----------------
__global__ __launch_bounds__(256) void kwprep(const float* __restrict__ Wh,
                                              unsigned short* __restrict__ Wt) {
  int idx = blockIdx.x * 256 + threadIdx.x;
  if (idx >= KCN * 2048) return;
  int kc = idx >> 11, r = idx & 2047, a = r >> 5, kk = r & 31;
  int d = kc * 32 + kk;
  float v = (a < A_ && d < D700) ? Wh[a * D700 + d] : 0.f;
  Wt[idx] = f2bf(v);
}

// ---------------- K2: u2[b][0..63] (fp32), 2 b's per block ----------------
__global__ __launch_bounds__(256) void ku2(const float* __restrict__ hidden,
                                           const int* __restrict__ e1,
                                           const int* __restrict__ e2,
                                           const float* __restrict__ Went,
                                           const float* __restrict__ lt,
                                           float* __restrict__ u2ws) {
  __shared__ __align__(16) float E[2][2400];   // [hid_e1|e1_type|hid_e2|e2_type]
  __shared__ float dots[2][2][3];
  __shared__ float aw[2][2][3];
  int tid = threadIdx.x;
  int b0 = blockIdx.x * 2;

  for (int idx = tid; idx < 2 * 2 * 150; idx += 256) {
    int i = idx / 300, r = idx - i * 300, e = r / 150, g = r - e * 150;
    int bb = b0 + i;
    int l = e ? e2[bb] : e1[bb];
    float4 f = *(const float4*)(hidden + ((size_t)bb * L_ + l) * H2_ + g * 4);
    *(float4*)(&E[i][e * 1200 + g * 4]) = f;
  }
  __syncthreads();

  int w = tid >> 6, lane = tid & 63;
  for (int task = w * 3; task < w * 3 + 3; ++task) {
    int i = task / 6, e = (task / 3) & 1, t = task % 3;
    float p = 0.f;
    for (int d = lane; d < 600; d += 64) p += E[i][e * 1200 + d] * lt[t * 600 + d];
    #pragma unroll
    for (int mask = 1; mask <= 32; mask <<= 1) p += __shfl_xor(p, mask);
    if (lane == 0) dots[i][e][t] = p;
  }
  __syncthreads();
  if (tid < 12) {
    int t = tid % 3, e = (tid / 3) & 1, i = tid / 6;
    float d0 = dots[i][e][0], d1 = dots[i][e][1], d2 = dots[i][e][2];
    float m = fmaxf(d0, fmaxf(d1, d2));
    float x0 = expf(d0 - m), x1 = expf(d1 - m), x2 = expf(d2 - m);
    float Z = x0 + x1 + x2;
    aw[i][e][t] = ((t == 0) ? x0 : (t == 1) ? x1 : x2) / Z;
  }
  __syncthreads();
  for (int idx = tid; idx < 2 * 2 * 600; idx += 256) {
    int i = idx / 1200, r = idx - i * 1200, e = r / 600, d = r - e * 600;
    float v = aw[i][e][0] * lt[d] + aw[i][e][1] * lt[600 + d] + aw[i][e][2] * lt[1200 + d];
    E[i][e * 1200 + 600 + d] = v;
  }
  __syncthreads();
  for (int a = w; a < A_; a += 4) {
    float acc[2] = {0.f, 0.f};
    for (int d0 = lane * 4; d0 < 2400; d0 += 256) {
      float4 wv = *(const float4*)(Went + a * 2400 + d0);
      #pragma unroll
      for (int i = 0; i < 2; ++i) {
        float4 ev = *(const float4*)(&E[i][d0]);
        acc[i] += ev.x * wv.x + ev.y * wv.y + ev.z * wv.z + ev.w * wv.w;
      }
    }
    #pragma unroll
    for (int i = 0; i < 2; ++i) {
      float p = acc[i];
      #pragma unroll
      for (int mask = 1; mask <= 32; mask <<= 1) p += __shfl_xor(p, mask);
      if (lane == 0) u2ws[(b0 + i) * AP + a] = p;
    }
  }
  for (int idx = tid; idx < 2 * (AP - A_); idx += 256) {
    u2ws[(b0 + idx / (AP - A_)) * AP + A_ + idx % (AP - A_)] = 0.f;
  }
}

// ---------------- K3: main fused kernel ----------------
__global__ __launch_bounds__(256, 4) void kmain(
    const float* __restrict__ hidden, const float* __restrict__ pos1,
    const float* __restrict__ pos2, const float* __restrict__ vvec,
    const unsigned short* __restrict__ Wt, const float* __restrict__ u2ws,
    float* __restrict__ zp_ws, float* __restrict__ mS_ws) {
  __shared__ __align__(16) unsigned short Xs[MT * XP];   // 22,784 B
  __shared__ float scores4[4][MT];
  __shared__ float es_s[MT];
  __shared__ float u2s[AP];
  __shared__ float vs[AP];

  int tid = threadIdx.x;
  int bq = blockIdx.x;
  int b = bq >> 3, o = bq & 7, tok0 = o * MT;
  int lane = tid & 63, wv = tid >> 6;
  int acol = lane & 15, kgrp = lane >> 4;

  // ======== PHASE 1: issue ALL global loads (deep VMEM queue) ========
  // hidden: row t = tid>>4, float4 col c0+16j  (no division)
  int t = tid >> 4, c0 = tid & 15;
  const float* rowp = hidden + ((size_t)(b * L_ + tok0) + t) * H2_;
  float4 f[9];
  #pragma unroll
  for (int j = 0; j < 9; ++j) f[j] = *(const float4*)(rowp + (c0 + 16 * j) * 4);
  bool h10 = (c0 < 6);
  float4 f9;
  if (h10) f9 = *(const float4*)(rowp + (c0 + 144) * 4);

  // pos1/pos2: 400 float2 each; thread covers idx=tid and idx=tid+256 (tid<144)
  const float* p1 = pos1 + (size_t)(b * L_ + tok0) * P_;
  const float* p2 = pos2 + (size_t)(b * L_ + tok0) * P_;
  float2 q1a = *(const float2*)(p1 + tid * 2);
  float2 q2a = *(const float2*)(p2 + tid * 2);
  bool hq = (tid < 144);
  float2 q1b, q2b;
  if (hq) {
    q1b = *(const float2*)(p1 + (tid + 256) * 2);
    q2b = *(const float2*)(p2 + (tid + 256) * 2);
  }
  // u2 / v (L2-resident)
  float u2v = 0.f, vvv = 0.f;
  if (tid < AP) {
    u2v = u2ws[b * AP + tid];
    vvv = (tid < A_) ? vvec[tid] : 0.f;
  }
  // W fragments, first half (L2-resident)
  const unsigned short* wbase = Wt + (wv * 16 + acol) * 32 + kgrp * 8;
  short8 wf1[KH];
  #pragma unroll
  for (int kc = 0; kc < KH; ++kc)
    wf1[kc] = *(const short8*)(wbase + kc * 2048);

  // ======== PHASE 2: convert + LDS writes ========
  #pragma unroll
  for (int j = 0; j < 9; ++j) {
    uint2 w; w.x = pk2(f[j].x, f[j].y); w.y = pk2(f[j].z, f[j].w);
    *(uint2*)(&Xs[t * XP + (c0 + 16 * j) * 4]) = w;
  }
  if (h10) {
    uint2 w; w.x = pk2(f9.x, f9.y); w.y = pk2(f9.z, f9.w);
    *(uint2*)(&Xs[t * XP + (c0 + 144) * 4]) = w;
  }
  {
    int t1 = tid / 25, g = tid - t1 * 25;           // idx = tid
    *(unsigned*)(&Xs[t1 * XP + 600 + g * 2]) = pk2(q1a.x, q1a.y);
    *(unsigned*)(&Xs[t1 * XP + 650 + g * 2]) = pk2(q2a.x, q2a.y);
  }
  if (hq) {
    int idx = tid + 256;
    int t1 = idx / 25, g = idx - t1 * 25;
    *(unsigned*)(&Xs[t1 * XP + 600 + g * 2]) = pk2(q1b.x, q1b.y);
    *(unsigned*)(&Xs[t1 * XP + 650 + g * 2]) = pk2(q2b.x, q2b.y);
  }
  if (tid < MT * 2) {
    int tt = tid >> 1, g = tid & 1;
    *(unsigned*)(&Xs[tt * XP + 700 + g * 2]) = 0u;
  }
  if (tid < AP) { u2s[tid] = u2v; vs[tid] = vvv; }
  __syncthreads();

  // ======== PHASE 3: MFMA K-loop, W half2 prefetched under half1 ========
  short8 wf2[KH];
  #pragma unroll
  for (int kc = 0; kc < KH; ++kc)
    wf2[kc] = *(const short8*)(wbase + (KH + kc) * 2048);

  f32x4 acc0 = {0.f, 0.f, 0.f, 0.f};
  #pragma unroll
  for (int kc = 0; kc < KH; ++kc) {
    short8 a0 = *(const short8*)(&Xs[acol * XP + kc * 32 + kgrp * 8]);
    acc0 = __builtin_amdgcn_mfma_f32_16x16x32_bf16(a0, wf1[kc], acc0, 0, 0, 0);
  }
  #pragma unroll
  for (int kc = 0; kc < KH; ++kc) {
    short8 a0 = *(const short8*)(&Xs[acol * XP + (KH + kc) * 32 + kgrp * 8]);
    acc0 = __builtin_amdgcn_mfma_f32_16x16x32_bf16(a0, wf2[kc], acc0, 0, 0, 0);
  }

  // ---- epilogue: scores = sum_a v[a]*tanh(u1+u2)
  {
    float va = vs[wv * 16 + acol];
    float u2a = u2s[wv * 16 + acol];
    float s0[4];
    #pragma unroll
    for (int r = 0; r < 4; ++r) s0[r] = va * tanhf(acc0[r] + u2a);
    #pragma unroll
    for (int mask = 1; mask < 16; mask <<= 1) {
      #pragma unroll
      for (int r = 0; r < 4; ++r) s0[r] += __shfl_xor(s0[r], mask);
    }
    if (acol == 0) {
      #pragma unroll
      for (int r = 0; r < 4; ++r) scores4[wv][kgrp * 4 + r] = s0[r];
    }
  }
  __syncthreads();

  // ---- partial softmax over this block's 16 tokens
  if (tid < 64) {
    float s = (tid < MT)
                  ? (scores4[0][tid] + scores4[1][tid] + scores4[2][tid] + scores4[3][tid])
                  : -3.402823466e38f;
    float m = s;
    #pragma unroll
    for (int mask = 1; mask <= 32; mask <<= 1) m = fmaxf(m, __shfl_xor(m, mask));
    float e = (tid < MT) ? expf(s - m) : 0.f;
    float S = e;
    #pragma unroll
    for (int mask = 1; mask <= 32; mask <<= 1) S += __shfl_xor(S, mask);
    if (tid < MT) es_s[tid] = e;
    if (tid == 0) { mS_ws[bq * 2] = m; mS_ws[bq * 2 + 1] = S; }
  }
  __syncthreads();

  // ---- z-partial: zp[d] = sum_l exp(s_l - m) * hidden_bf16[l][d]
  if (tid < 75) {
    float acc[8] = {0.f, 0.f, 0.f, 0.f, 0.f, 0.f, 0.f, 0.f};
    #pragma unroll
    for (int tt = 0; tt < MT; ++tt) {
      short8 xv = *(const short8*)(&Xs[tt * XP + tid * 8]);
      float e = es_s[tt];
      #pragma unroll
      for (int j = 0; j < 8; ++j) acc[j] += e * bf2f((unsigned short)xv[j]);
    }
    float4 w0 = {acc[0], acc[1], acc[2], acc[3]};
    float4 w1 = {acc[4], acc[5], acc[6], acc[7]};
    *(float4*)(zp_ws + (size_t)bq * 600 + tid * 8) = w0;
    *(float4*)(zp_ws + (size_t)bq * 600 + tid * 8 + 4) = w1;
  }
}

// ---------------- K4: combine 8 partials per b ----------------
__global__ __launch_bounds__(128) void kcomb(const float* __restrict__ zp_ws,
                                             const float* __restrict__ mS_ws,
                                             float* __restrict__ out) {
  int b = blockIdx.x, tid = threadIdx.x;
  float mq[8], Sq[8];
  #pragma unroll
  for (int qq = 0; qq < 8; ++qq) {
    mq[qq] = mS_ws[(b * 8 + qq) * 2];
    Sq[qq] = mS_ws[(b * 8 + qq) * 2 + 1];
  }
  float M = mq[0];
  #pragma unroll
  for (int qq = 1; qq < 8; ++qq) M = fmaxf(M, mq[qq]);
  float c[8], Z = 0.f;
  #pragma unroll
  for (int qq = 0; qq < 8; ++qq) { c[qq] = expf(mq[qq] - M); Z += Sq[qq] * c[qq]; }
  float inv = 1.f / Z;
  for (int d = tid; d < 600; d += 128) {
    float z = 0.f;
    #pragma unroll
    for (int qq = 0; qq < 8; ++qq) z += c[qq] * zp_ws[(size_t)(b * 8 + qq) * 600 + d];
    out[b * 600 + d] = z * inv;
  }
}

extern "C" void kernel_launch(void* const* d_in, const int* in_sizes, int n_in,
                              void* d_out, int out_size, void* d_ws, size_t ws_size,
                              hipStream_t stream) {
  const float* hidden = (const float*)d_in[0];
  const float* pos1   = (const float*)d_in[1];
  const float* pos2   = (const float*)d_in[2];
  const int*   e1     = (const int*)d_in[3];
  const int*   e2     = (const int*)d_in[4];
  const float* Whid   = (const float*)d_in[5];
  const float* Went   = (const float*)d_in[6];
  const float* lt     = (const float*)d_in[7];
  const float* vvec   = (const float*)d_in[8];
  float* out = (float*)d_out;

  char* ws = (char*)d_ws;
  unsigned short* Wt = (unsigned short*)ws;                       //  90,112 B (pad 98,304)
  float* u2ws  = (float*)(ws + 98304);                            // 524,288 B
  float* mS_ws = (float*)(ws + 98304 + 524288);                   // 131,072 B
  float* zp_ws = (float*)(ws + 98304 + 524288 + 131072);          // 39,321,600 B

  hipLaunchKernelGGL(kwprep, dim3(176), dim3(256), 0, stream, Whid, Wt);
  hipLaunchKernelGGL(ku2, dim3(B_ / 2), dim3(256), 0, stream, hidden, e1, e2, Went, lt, u2ws);
  hipLaunchKernelGGL(kmain, dim3(B_ * 8), dim3(256), 0, stream, hidden, pos1, pos2, vvec,
                     Wt, u2ws, zp_ws, mS_ws);
  hipLaunchKernelGGL(kcomb, dim3(B_), dim3(128), 0, stream, zp_ws, mS_ws, out);
}